// Round 13
// baseline (5482.010 us; speedup 1.0000x reference)
//
#include <hip/hip_runtime.h>
#include <cstdint>
#include <cstddef>

// R13: R12 + forced VGPR budget. rocprof showed VGPR_Count=128 (compiler
// budgeted 4 waves/SIMD) -> the 192-u32 W_hh slice spilled/rematerialized,
// costing ~10k cy/step of L2 re-reads (WRITE_SIZE +31MB spill signature).
// Fix: amdgpu_waves_per_eu(2,2) — this kernel runs exactly 2 waves/EU
// (512 thr, 130KB LDS => 1 WG/CU), so budget VGPRs for 2 waves/EU = 256.
// Plus opaque-asm pin on each packed weight to forbid rematerialization.
// Everything else identical to R12 (passed, absmax 0.0039).

#define BB 64
#define TT 1024
#define II 64
#define HH 512
#define OO 64

typedef __fp16 h2_t __attribute__((ext_vector_type(2)));

__device__ __forceinline__ unsigned pk16(float a, float b) {
  h2_t h = __builtin_amdgcn_cvt_pkrtz(a, b);
  return __builtin_bit_cast(unsigned, h);
}

__device__ __forceinline__ float fdot2u(unsigned a, unsigned b, float c) {
#if __has_builtin(__builtin_amdgcn_fdot2)
  return __builtin_amdgcn_fdot2(__builtin_bit_cast(h2_t, a),
                                __builtin_bit_cast(h2_t, b), c, false);
#else
  h2_t x = __builtin_bit_cast(h2_t, a), y = __builtin_bit_cast(h2_t, b);
  return c + (float)x[0] * (float)y[0] + (float)x[1] * (float)y[1];
#endif
}

__device__ __forceinline__ float tanh_fast(float v) {
  float e = exp2f(fabsf(v) * 2.8853900817779268f);
  float r = 1.0f - 2.0f * __builtin_amdgcn_rcpf(e + 1.0f);
  return copysignf(r, v);
}

// ---- prep: pack Wih [512x64] and Wout [64x512] fp32 -> f16-pair u32 ----
__global__ void prep_pack(const float* __restrict__ Wih,
                          const float* __restrict__ Wout,
                          unsigned* __restrict__ wsWih,
                          unsigned* __restrict__ wsWout) {
  const int i = blockIdx.x * 256 + threadIdx.x;  // 0..32767
  if (i < 16384) {            // Wih: r = i>>5, pair m = i&31
    const float2 v = *(const float2*)(Wih + (size_t)(i >> 5) * II + (i & 31) * 2);
    wsWih[i] = pk16(v.x, v.y);
  } else {                    // Wout: o = k>>8, pair m = k&255
    const int k = i - 16384;
    const float2 v = *(const float2*)(Wout + (size_t)(k >> 8) * HH + (k & 255) * 2);
    wsWout[k] = pk16(v.x, v.y);
  }
}

__global__ __attribute__((amdgpu_flat_work_group_size(512, 512),
                          amdgpu_waves_per_eu(2, 2)))
void rnn_onecu(
    const float* __restrict__ x, const float* __restrict__ h0,
    const float* __restrict__ Whh, const float* __restrict__ bih,
    const float* __restrict__ bhh, const float* __restrict__ bout,
    const unsigned* __restrict__ wsWih, const unsigned* __restrict__ wsWout,
    float* __restrict__ out) {
  const int tid = threadIdx.x;
  const int b   = blockIdx.x;
  const int g   = tid >> 3;   // row-group: rows 8g..8g+7
  const int c   = tid & 7;    // k-chunk: k in [64c, 64c+64)

  // LDS: Whh tail (16 k/row) + h double-buffer (f16 pairs, padded chunks) + x
  __shared__ unsigned ldsW[16][512][4];   // 128 KB
  __shared__ unsigned hsl[2][8][36];      // [slot][chunk][32 used + 4 pad]
  __shared__ unsigned xsl[2][32];         // x[t] as f16 pairs

  // ---- prologue: Whh rows -> f16 pairs: 24 u32/row regs + 8 u32/row LDS ----
  unsigned wh[8][24];
#pragma unroll
  for (int j = 0; j < 8; ++j) {
    const float* base = Whh + (size_t)(8 * g + j) * HH + c * 64;
#pragma unroll
    for (int m = 0; m < 32; ++m) {
      const float2 w2 = *(const float2*)(base + 2 * m);
      unsigned pw = pk16(w2.x, w2.y);
      if (m < 24) {
        asm volatile("" : "+v"(pw));   // opaque: forbid remat from the load
        wh[j][m] = pw;
      } else {
        const int flat = j * 8 + (m - 24);          // 0..63
        ldsW[flat >> 2][tid][flat & 3] = pw;
      }
    }
  }
  const float bsum = bih[tid] + bhh[tid];   // thread finalizes row `tid`
  const float bo   = bout[tid >> 3];        // for out-proj lanes (kc==0 uses)

  // stage h0 (f16 pairs) into slot 0
  {
    const float v  = h0[(size_t)b * HH + tid];
    const float pv = __shfl_xor(v, 1);
    if (!(tid & 1)) {
      const int m = tid >> 1;
      hsl[0][m >> 5][m & 31] = pk16(v, pv);
    }
  }
  // pre-stage x[0] into slot 1 (consumed at t=1)
  const bool xloader = (tid >= 448 && tid < 464);
  const int  xl      = tid - 448;
  if (xloader) {
    const float4 v = *(const float4*)(x + (size_t)b * TT * II + xl * 4);
    xsl[1][xl * 2]     = pk16(v.x, v.y);
    xsl[1][xl * 2 + 1] = pk16(v.z, v.w);
  }
  __syncthreads();

  const unsigned* wip = wsWih + tid * 32;               // this row's Wih slice
  const unsigned* wop = wsWout + (tid >> 3) * 256 + (tid & 7) * 32;
  float* outb = out + (size_t)b * TT * OO;

  for (int t = 1; t <= TT + 1; ++t) {
    const int p = (t - 1) & 1;   // h_{t-1} slot; x[t-1] is in slot t&1 = 1-p

    // prefetch+stage x[t] into slot (t+1)&1 == p (read next step, after barrier)
    if (t < TT && xloader) {
      const float4 v = *(const float4*)(x + ((size_t)b * TT + t) * II + xl * 4);
      xsl[p][xl * 2]     = pk16(v.x, v.y);
      xsl[p][xl * 2 + 1] = pk16(v.z, v.w);
    }

    if (t <= TT) {
      // ---- recurrent matvec: 8 rows x 64 k per thread ----
      float acc[8];
#pragma unroll
      for (int j = 0; j < 8; ++j) acc[j] = 0.0f;

#pragma unroll
      for (int blk = 0; blk < 3; ++blk) {   // 48 k from registers
        const uint4 h0v = *(const uint4*)&hsl[p][c][blk * 8];
        const uint4 h1v = *(const uint4*)&hsl[p][c][blk * 8 + 4];
#pragma unroll
        for (int j = 0; j < 8; ++j) {
          acc[j] = fdot2u(wh[j][blk * 8 + 0], h0v.x, acc[j]);
          acc[j] = fdot2u(wh[j][blk * 8 + 1], h0v.y, acc[j]);
          acc[j] = fdot2u(wh[j][blk * 8 + 2], h0v.z, acc[j]);
          acc[j] = fdot2u(wh[j][blk * 8 + 3], h0v.w, acc[j]);
          acc[j] = fdot2u(wh[j][blk * 8 + 4], h1v.x, acc[j]);
          acc[j] = fdot2u(wh[j][blk * 8 + 5], h1v.y, acc[j]);
          acc[j] = fdot2u(wh[j][blk * 8 + 6], h1v.z, acc[j]);
          acc[j] = fdot2u(wh[j][blk * 8 + 7], h1v.w, acc[j]);
        }
      }
      {  // 16 k from LDS tail
        const uint4 h0v = *(const uint4*)&hsl[p][c][24];
        const uint4 h1v = *(const uint4*)&hsl[p][c][28];
        const unsigned hx[8] = {h0v.x, h0v.y, h0v.z, h0v.w,
                                h1v.x, h1v.y, h1v.z, h1v.w};
#pragma unroll
        for (int mm = 0; mm < 16; ++mm) {
          const uint4 wv = *(const uint4*)&ldsW[mm][tid][0];
          const unsigned wa[4] = {wv.x, wv.y, wv.z, wv.w};
#pragma unroll
          for (int e = 0; e < 4; ++e) {
            const int idx = mm * 4 + e;
            acc[idx >> 3] = fdot2u(wa[e], hx[idx & 7], acc[idx >> 3]);
          }
        }
      }
      // reduce over k-chunks (8 lanes, xor butterfly)
#pragma unroll
      for (int m = 1; m < 8; m <<= 1) {
#pragma unroll
        for (int j = 0; j < 8; ++j) acc[j] += __shfl_xor(acc[j], m);
      }
      // thread tid's row total = acc[c]
      float val = acc[0];
#pragma unroll
      for (int j = 1; j < 8; ++j) val = (c == j) ? acc[j] : val;

      // ---- x-projection: row tid, Wih f16 slice from global (L1/L2) ----
#pragma unroll
      for (int pass = 0; pass < 4; ++pass) {
        const uint4 a0 = *(const uint4*)(wip + pass * 8);
        const uint4 a1 = *(const uint4*)(wip + pass * 8 + 4);
        const uint4 b0 = *(const uint4*)&xsl[1 - p][pass * 8];
        const uint4 b1 = *(const uint4*)&xsl[1 - p][pass * 8 + 4];
        val = fdot2u(a0.x, b0.x, val); val = fdot2u(a0.y, b0.y, val);
        val = fdot2u(a0.z, b0.z, val); val = fdot2u(a0.w, b0.w, val);
        val = fdot2u(a1.x, b1.x, val); val = fdot2u(a1.y, b1.y, val);
        val = fdot2u(a1.z, b1.z, val); val = fdot2u(a1.w, b1.w, val);
      }

      const float hf = tanh_fast(val + bsum);
      // write h_t (f16 pairs) into slot t&1 == 1-p
      const float pv = __shfl_xor(hf, 1);
      if (!(tid & 1)) {
        const int m = tid >> 1;
        hsl[1 - p][m >> 5][m & 31] = pk16(hf, pv);
      }
      if (t == TT) {  // final hidden state (fp32)
        out[(size_t)BB * TT * OO + (size_t)b * HH + tid] = hf;
      }
    }

    // ---- out-projection for tau = t-1 (h_{t-1} in slot p, still live) ----
    if (t >= 2) {
      const int o = tid >> 3, kc = tid & 7;
      float s = 0.0f;
#pragma unroll
      for (int pass = 0; pass < 4; ++pass) {
        const uint4 a0 = *(const uint4*)(wop + pass * 8);
        const uint4 a1 = *(const uint4*)(wop + pass * 8 + 4);
        const uint4 b0 = *(const uint4*)&hsl[p][kc][pass * 8];
        const uint4 b1 = *(const uint4*)&hsl[p][kc][pass * 8 + 4];
        s = fdot2u(a0.x, b0.x, s); s = fdot2u(a0.y, b0.y, s);
        s = fdot2u(a0.z, b0.z, s); s = fdot2u(a0.w, b0.w, s);
        s = fdot2u(a1.x, b1.x, s); s = fdot2u(a1.y, b1.y, s);
        s = fdot2u(a1.z, b1.z, s); s = fdot2u(a1.w, b1.w, s);
      }
      s += __shfl_xor(s, 1);
      s += __shfl_xor(s, 2);
      s += __shfl_xor(s, 4);
      if (kc == 0) {
        outb[(size_t)(t - 2) * OO + o] = tanh_fast(s + bo);
      }
    }

    __syncthreads();
  }
}

extern "C" void kernel_launch(void* const* d_in, const int* in_sizes, int n_in,
                              void* d_out, int out_size, void* d_ws, size_t ws_size,
                              hipStream_t stream) {
  (void)in_sizes; (void)n_in; (void)out_size; (void)ws_size;
  const float* x    = (const float*)d_in[0];
  const float* h0   = (const float*)d_in[1];
  const float* Wih  = (const float*)d_in[2];
  const float* Whh  = (const float*)d_in[3];
  const float* bih  = (const float*)d_in[4];
  const float* bhh  = (const float*)d_in[5];
  const float* Wout = (const float*)d_in[6];
  const float* bout = (const float*)d_in[7];
  float* out = (float*)d_out;

  unsigned char* ws = (unsigned char*)d_ws;
  unsigned* wsWih  = (unsigned*)ws;              // 16384 u32 = 64 KB
  unsigned* wsWout = (unsigned*)(ws + 65536);    // 16384 u32 = 64 KB

  prep_pack<<<dim3(128), dim3(256), 0, stream>>>(Wih, Wout, wsWih, wsWout);
  rnn_onecu<<<dim3(64), dim3(512), 0, stream>>>(
      x, h0, Whh, bih, bhh, bout, wsWih, wsWout, out);
}